// Round 1
// baseline (148.721 us; speedup 1.0000x reference)
//
#include <hip/hip_runtime.h>

#define BB    2048
#define TT    1024
#define TAILN 8
#define NSEQ  (BB * TAILN)          // 16384 independent sequences
#define NELEM (BB * TT * TAILN)     // 16,777,216 elements per array

// ---------------------------------------------------------------------------
// terminated-dtype detection (bool u8 / int32 / float32), deterministic.
// Words of the buffer:
//   int32 data  -> every word is 0 or 1            (no evidence)
//   float data  -> words are 0 or 0x3F800000       (evidence bit 2)
//   bool bytes  -> words have bytes in {0,1}; any word>1 is bool evidence
//                  (0x3F800000 impossible: bytes 0x3F/0x80 not in {0,1})
// ---------------------------------------------------------------------------
static __global__ void zero_flag_kernel(int* flag) {
    if (threadIdx.x == 0 && blockIdx.x == 0) *flag = 0;
}

static __global__ void detect_kernel(const unsigned int* __restrict__ term,
                                     int* __restrict__ flag) {
    unsigned tid = blockIdx.x * blockDim.x + threadIdx.x;
    int ev = 0;
    // Scan 64K words = 256KB; safe under all hypotheses (buffer >= 16MB).
    // At 1% termination density each hypothesis yields abundant evidence.
    for (unsigned i = tid; i < 65536u; i += blockDim.x * gridDim.x) {
        unsigned w = term[i];
        if (w == 0x3F800000u)      ev |= 2;   // float 1.0f
        else if (w > 1u)           ev |= 1;   // packed bool bytes
    }
    if (ev) atomicOr(flag, ev);
}

// ---------------------------------------------------------------------------
// main GAE kernel: one thread per (b, tail) sequence, backward scan over T.
// ---------------------------------------------------------------------------
template <int MODE>
__device__ __forceinline__ void gae_seq(int sid,
    const float* __restrict__ reward, const void* __restrict__ termv,
    const float* __restrict__ value,  const float* __restrict__ next_value,
    float* __restrict__ adv, float* __restrict__ ret)
{
    const float g  = 0.99f;
    const float gl = (float)(0.99 * 0.95);
    const unsigned char* tb = (const unsigned char*)termv;
    const int*           ti = (const int*)termv;
    const float*         tf = (const float*)termv;

    // element index for (b, t, tail): b*T*TAIL + t*TAIL + tail
    const int base = (sid >> 3) * (TT * TAILN) + (sid & 7);

    float gae = 0.0f;
    #pragma unroll 8
    for (int t = TT - 1; t >= 0; --t) {
        const int idx = base + t * TAILN;
        float nd;
        if (MODE == 1)      nd = tb[idx] ? 0.0f : 1.0f;   // bool bytes
        else if (MODE == 2) nd = 1.0f - tf[idx];          // float32
        else                nd = ti[idx] ? 0.0f : 1.0f;   // int32
        const float v = value[idx];
        const float d = fmaf(g * nd, next_value[idx], reward[idx]) - v;
        gae = fmaf(gl * nd, gae, d);
        adv[idx] = gae;
        ret[idx] = gae + v;
    }
}

__global__ __launch_bounds__(64)
void gae_kernel(const float* __restrict__ reward, const void* __restrict__ term,
                const float* __restrict__ value,  const float* __restrict__ next_value,
                float* __restrict__ adv, float* __restrict__ ret,
                const int* __restrict__ flag)
{
    const int sid = blockIdx.x * blockDim.x + threadIdx.x;
    if (sid >= NSEQ) return;
    const int f = *flag;                 // wave-uniform
    if (f & 1)      gae_seq<1>(sid, reward, term, value, next_value, adv, ret);
    else if (f & 2) gae_seq<2>(sid, reward, term, value, next_value, adv, ret);
    else            gae_seq<0>(sid, reward, term, value, next_value, adv, ret);
}

extern "C" void kernel_launch(void* const* d_in, const int* in_sizes, int n_in,
                              void* d_out, int out_size, void* d_ws, size_t ws_size,
                              hipStream_t stream) {
    const float* reward = (const float*)d_in[0];
    const void*  term   = d_in[1];
    const float* value  = (const float*)d_in[2];
    const float* nextv  = (const float*)d_in[3];
    float* adv = (float*)d_out;             // advantages: first NELEM floats
    float* ret = adv + NELEM;               // returns:    next NELEM floats
    int*   flag = (int*)d_ws;

    hipLaunchKernelGGL(zero_flag_kernel, dim3(1), dim3(64), 0, stream, flag);
    hipLaunchKernelGGL(detect_kernel, dim3(32), dim3(256), 0, stream,
                       (const unsigned int*)term, flag);
    // block=64, grid=256 -> one wave per CU across all 256 CUs
    hipLaunchKernelGGL(gae_kernel, dim3(NSEQ / 64), dim3(64), 0, stream,
                       reward, term, value, nextv, adv, ret, flag);
}